// Round 7
// baseline (97.092 us; speedup 1.0000x reference)
//
#include <hip/hip_runtime.h>
#include <hip/hip_cooperative_groups.h>
#include <math.h>

namespace cg = cooperative_groups;

#define B_    32
#define PPB   256
#define N_    (B_*PPB)     // 8192 proposals / padded slots
#define M_    128
#define LANG_ 256
#define H_    128
#define EPS_  1e-5f
#define MC    16           // columns per block
#define NBLK  (N_/MC)      // 512 blocks

typedef __attribute__((ext_vector_type(8))) short s16x8;
typedef __attribute__((ext_vector_type(4))) float f32x4;

static __device__ __forceinline__ unsigned short f2bf(float x) {
  unsigned int u = __float_as_uint(x);
  unsigned int r = (u + 0x7fff + ((u >> 16) & 1)) >> 16;
  return (unsigned short)r;
}
static __device__ __forceinline__ float bf2f(unsigned short h) {
  return __uint_as_float(((unsigned int)h) << 16);
}

#define MFMA_LAYER(Aarr)                                                     \
  {                                                                          \
    _Pragma("unroll")                                                        \
    for (int sg = 0; sg < 8; ++sg) {                                         \
      const s16x8 bb = (sg < 4) ? Bh[sg] : Bl[sg - 4];                       \
      acc[0] = __builtin_amdgcn_mfma_f32_16x16x32_bf16(Aarr[0][sg], bb, acc[0], 0, 0, 0); \
      acc[1] = __builtin_amdgcn_mfma_f32_16x16x32_bf16(Aarr[1][sg], bb, acc[1], 0, 0, 0); \
    }                                                                        \
    _Pragma("unroll")                                                        \
    for (int sg = 0; sg < 8; ++sg) {                                         \
      const s16x8 bb = (sg < 4) ? Bl[sg] : Bh[sg - 4];                       \
      acc[0] = __builtin_amdgcn_mfma_f32_16x16x32_bf16(Aarr[0][sg], bb, acc[0], 0, 0, 0); \
      acc[1] = __builtin_amdgcn_mfma_f32_16x16x32_bf16(Aarr[1][sg], bb, acc[1], 0, 0, 0); \
    }                                                                        \
  }

#define READ_B()                                                             \
  {                                                                          \
    _Pragma("unroll")                                                        \
    for (int s = 0; s < 4; ++s) {                                            \
      const int idx = (s * 4 + g) * 16 + o16;                                \
      Bh[s] = XbHi[idx];                                                     \
      Bl[s] = XbLo[idx];                                                     \
    }                                                                        \
  }

#define LOAD_A(Aarr, LL)                                                     \
  {                                                                          \
    _Pragma("unroll")                                                        \
    for (int t = 0; t < 2; ++t)                                              \
      _Pragma("unroll")                                                      \
      for (int s = 0; s < 8; ++s)                                            \
        Aarr[t][s] = *reinterpret_cast<const s16x8*>(                        \
            wa + (size_t)(((LL) * 8 + s) * 8 + (wid * 2 + t)) * 512 + lane * 8); \
  }

// ---------------------------------------------------------------------------
// ONE cooperative kernel. 512 blocks x 256 threads.
// Pre-sync:  blocks 0-31  = bin-parallel mapping (block b owns bin b; scans
//                           all 8192 first-points, ranks via scans, scatters
//                           srcmap directly — no cross-block communication)
//            blocks 32-63 = frag-major hi/lo bf16 weight build (wa)
//            blocks 64-95 = lang projection lp[b][o]
//            ALL blocks   = BN-fold params into LDS pbuf[128..1023]
// grid.sync()
// Post-sync: r6's MFMA MLP body (16 cols/block, hi/lo split, 2 passes/layer).
// ---------------------------------------------------------------------------
__global__ __launch_bounds__(256, 2) void k_all(
    const float* __restrict__ feats,
    const int* __restrict__ pidx, const int* __restrict__ poff,
    const int* __restrict__ boff, const float* __restrict__ langg,
    const float* __restrict__ Wf, const float* __restrict__ bf,
    const float* __restrict__ W1, const float* __restrict__ b1,
    const float* __restrict__ g1, const float* __restrict__ be1,
    const float* __restrict__ rm1, const float* __restrict__ rv1,
    const float* __restrict__ W2, const float* __restrict__ b2,
    const float* __restrict__ g2, const float* __restrict__ be2,
    const float* __restrict__ rm2, const float* __restrict__ rv2,
    const float* __restrict__ W3, const float* __restrict__ b3,
    int* __restrict__ srcmap, float* __restrict__ lp,
    unsigned short* __restrict__ wa,
    float* __restrict__ out)
{
  __shared__ s16x8 XbHi[256];      // [sg16][n16] frags (4 KB)
  __shared__ s16x8 XbLo[256];      // (4 KB)
  __shared__ float pbuf[1024];     // (4 KB)
  __shared__ float outp[64];
  __shared__ int   wtot[4];

  cg::grid_group grid = cg::this_grid();

  const int tid = threadIdx.x;
  const int lane = tid & 63, wid = tid >> 6;
  const int o16 = lane & 15, g = lane >> 4;
  const int blk = blockIdx.x;

  // ======================= pre-sync phase =======================
  // pbuf[128..1023]: BN folds + W3 (reads raw inputs only) — all blocks
  #pragma unroll
  for (int j = 128 + tid; j < 1024; j += 256) {
    const int arr = j >> 7, o = j & 127;
    float v;
    switch (arr) {
      case 1: v = b1[o]; break;
      case 2: v = g1[o] * rsqrtf(rv1[o] + EPS_); break;
      case 3: { const float s = g1[o] * rsqrtf(rv1[o] + EPS_);
                v = be1[o] - rm1[o] * s; } break;
      case 4: v = b2[o]; break;
      case 5: v = g2[o] * rsqrtf(rv2[o] + EPS_); break;
      case 6: { const float s = g2[o] * rsqrtf(rv2[o] + EPS_);
                v = be2[o] - rm2[o] * s; } break;
      default: v = W3[o]; break;
    }
    pbuf[j] = v;
  }

  if (blk < 32) {
    // ---- bin-parallel mapping: block blk owns bin blk
    const int blo = boff[blk], bhi = boff[blk + 1];
    srcmap[blk * PPB + tid] = -1;          // init own bin
    const int i0 = tid * 32;
    unsigned mask = 0u;
    #pragma unroll
    for (int j = 0; j < 32; ++j) {
      const int off = poff[i0 + j];
      const int fp  = pidx[2 * off + 1];
      mask |= (fp >= blo && fp < bhi) ? (1u << j) : 0u;
    }
    const int cnt = __popc(mask);
    int sc = cnt;                          // inclusive wave scan
    #pragma unroll
    for (int d = 1; d < 64; d <<= 1) {
      const int v = __shfl_up(sc, d);
      if (lane >= d) sc += v;
    }
    if (lane == 63) wtot[wid] = sc;
    __syncthreads();                       // orders -1 init vs scatter too
    int base = sc - cnt;
    #pragma unroll
    for (int w = 0; w < 4; ++w) if (w < wid) base += wtot[w];
    unsigned m = mask;
    int r = base;
    while (m) {
      const int j = __ffs(m) - 1;
      if (r < PPB) srcmap[blk * PPB + r] = i0 + j;   // OOB dropped (.at.set)
      ++r;
      m &= m - 1;
    }
  } else if (blk < 64) {
    // ---- wa build: 6 frag-groups per block, one per wave pass
    for (int sub = wid; sub < 6; sub += 4) {
      const int G = (blk - 32) * 6 + sub;  // 0..191
      const int L = G >> 6, s = (G >> 3) & 7, t = G & 7;
      const float* Wsrc; int str;
      if (L == 0)      { Wsrc = Wf; str = 384; }
      else if (L == 1) { Wsrc = W1; str = H_; }
      else             { Wsrc = W2; str = H_; }
      const int o = t * 16 + o16, sp = s & 3;
      const bool hi = (s < 4);
      const float* rowp = Wsrc + (size_t)o * str + sp * 32 + g * 4;
      const float4 a = *reinterpret_cast<const float4*>(rowp);
      const float4 bq = *reinterpret_cast<const float4*>(rowp + 16);
      const float av[8] = {a.x, a.y, a.z, a.w, bq.x, bq.y, bq.z, bq.w};
      s16x8 v;
      #pragma unroll
      for (int e = 0; e < 8; ++e) {
        const unsigned short h = f2bf(av[e]);
        v[e] = (short)(hi ? h : f2bf(av[e] - bf2f(h)));
      }
      *reinterpret_cast<s16x8*>(wa + (size_t)G * 512 + lane * 8) = v;
    }
  } else if (blk < 96) {
    // ---- lang projection for batch blk-64: 2 threads per output channel
    const int bb = blk - 64;
    const int o = tid >> 1, hf = tid & 1;
    float acc = 0.f;
    const int l0 = hf * 128;
    #pragma unroll 8
    for (int l = l0; l < l0 + 128; l += 4) {
      const float4 w = *reinterpret_cast<const float4*>(Wf + o * 384 + 128 + l);
      const float4 e = *reinterpret_cast<const float4*>(langg + bb * LANG_ + l);
      acc += w.x * e.x + w.y * e.y + w.z * e.z + w.w * e.w;
    }
    acc += __shfl_xor(acc, 1);
    if (hf == 0) lp[bb * H_ + o] = acc;
  }

  grid.sync();

  // ======================= MLP phase =======================
  const int q0 = blk * MC;
  const int b = blk >> 4;                  // 16 blocks per batch

  s16x8 A0[2][8], A1[2][8], A2[2][8];
  LOAD_A(A0, 0);                           // issue early, in flight below

  if (tid < 128) pbuf[tid] = bf[tid] + lp[b * H_ + tid];

  // gather feats (hi/lo split) into Xb: frag (s,gg) x col n
  {
    const int n = tid & 15, u = tid >> 4;
    const int s = u >> 2, gg = u & 3;
    const int srow = srcmap[q0 + n];
    const int k0 = s * 32 + gg * 4;
    float4 a = make_float4(0.f, 0.f, 0.f, 0.f), bq = a;
    if (srow >= 0) {
      a  = *reinterpret_cast<const float4*>(feats + (size_t)srow * M_ + k0);
      bq = *reinterpret_cast<const float4*>(feats + (size_t)srow * M_ + k0 + 16);
    }
    const float av[8] = {a.x, a.y, a.z, a.w, bq.x, bq.y, bq.z, bq.w};
    s16x8 hv, lv;
    #pragma unroll
    for (int e = 0; e < 8; ++e) {
      const unsigned short h = f2bf(av[e]);
      hv[e] = (short)h;
      lv[e] = (short)f2bf(av[e] - bf2f(h));
    }
    XbHi[u * 16 + n] = hv;
    XbLo[u * 16 + n] = lv;
  }
  __syncthreads();

  f32x4 acc[2];
  s16x8 Bh[4], Bl[4];

  // ================= Layer 0 =================
  READ_B();
  __syncthreads();
  LOAD_A(A1, 1);
  acc[0] = (f32x4){0.f, 0.f, 0.f, 0.f};
  acc[1] = (f32x4){0.f, 0.f, 0.f, 0.f};
  MFMA_LAYER(A0);
  {
    s16x8 hv, lv;
    #pragma unroll
    for (int t = 0; t < 2; ++t)
      #pragma unroll
      for (int r = 0; r < 4; ++r) {
        const int o = (wid * 2 + t) * 16 + g * 4 + r;
        const float v = fmaxf(acc[t][r] + pbuf[o], 0.f);
        const unsigned short h = f2bf(v);
        hv[t * 4 + r] = (short)h;
        lv[t * 4 + r] = (short)f2bf(v - bf2f(h));
      }
    const int widx = (wid * 4 + g) * 16 + o16;
    XbHi[widx] = hv;
    XbLo[widx] = lv;
  }
  __syncthreads();

  // ================= Layer 1 =================
  READ_B();
  __syncthreads();
  LOAD_A(A2, 2);
  acc[0] = (f32x4){0.f, 0.f, 0.f, 0.f};
  acc[1] = (f32x4){0.f, 0.f, 0.f, 0.f};
  MFMA_LAYER(A1);
  {
    s16x8 hv, lv;
    #pragma unroll
    for (int t = 0; t < 2; ++t)
      #pragma unroll
      for (int r = 0; r < 4; ++r) {
        const int o = (wid * 2 + t) * 16 + g * 4 + r;
        const float v = fmaxf(acc[t][r] + pbuf[128 + o], 0.f) * pbuf[256 + o]
                        + pbuf[384 + o];
        const unsigned short h = f2bf(v);
        hv[t * 4 + r] = (short)h;
        lv[t * 4 + r] = (short)f2bf(v - bf2f(h));
      }
    const int widx = (wid * 4 + g) * 16 + o16;
    XbHi[widx] = hv;
    XbLo[widx] = lv;
  }
  __syncthreads();

  // ================= Layer 2 + epilogue =================
  READ_B();
  acc[0] = (f32x4){0.f, 0.f, 0.f, 0.f};
  acc[1] = (f32x4){0.f, 0.f, 0.f, 0.f};
  MFMA_LAYER(A2);
  {
    float p0 = 0.f;
    #pragma unroll
    for (int t = 0; t < 2; ++t)
      #pragma unroll
      for (int r = 0; r < 4; ++r) {
        const int o = (wid * 2 + t) * 16 + g * 4 + r;
        p0 += pbuf[896 + o] *
              (fmaxf(acc[t][r] + pbuf[512 + o], 0.f) * pbuf[640 + o] + pbuf[768 + o]);
      }
    p0 += __shfl_xor(p0, 16);
    p0 += __shfl_xor(p0, 32);
    if (lane < 16) outp[wid * 16 + lane] = p0;
    __syncthreads();
    if (tid < 16)
      out[q0 + tid] = outp[tid] + outp[16 + tid] + outp[32 + tid] + outp[48 + tid] + b3[0];
  }
}

// ---------------------------------------------------------------------------
extern "C" void kernel_launch(void* const* d_in, const int* in_sizes, int n_in,
                              void* d_out, int out_size, void* d_ws, size_t ws_size,
                              hipStream_t stream) {
  const float* feats = (const float*)d_in[0];
  const int*   pidx  = (const int*)d_in[1];
  const int*   poff  = (const int*)d_in[2];
  const int*   boff  = (const int*)d_in[3];
  const float* lang  = (const float*)d_in[4];
  const float* Wf    = (const float*)d_in[5];
  const float* bf    = (const float*)d_in[6];
  const float* W1    = (const float*)d_in[7];
  const float* b1    = (const float*)d_in[8];
  const float* g1    = (const float*)d_in[9];
  const float* be1   = (const float*)d_in[10];
  const float* rm1   = (const float*)d_in[11];
  const float* rv1   = (const float*)d_in[12];
  const float* W2    = (const float*)d_in[13];
  const float* b2    = (const float*)d_in[14];
  const float* g2    = (const float*)d_in[15];
  const float* be2   = (const float*)d_in[16];
  const float* rm2   = (const float*)d_in[17];
  const float* rv2   = (const float*)d_in[18];
  const float* W3    = (const float*)d_in[19];
  const float* b3    = (const float*)d_in[20];
  float* out = (float*)d_out;

  int*            srcmap = (int*)d_ws;                           // 32768 B
  float*          lp     = (float*)((char*)d_ws + 32768);        // 16384 B
  unsigned short* wa     = (unsigned short*)((char*)d_ws + 49152); // 196608 B

  void* args[] = { (void*)&feats, (void*)&pidx, (void*)&poff, (void*)&boff,
                   (void*)&lang, (void*)&Wf, (void*)&bf,
                   (void*)&W1, (void*)&b1, (void*)&g1, (void*)&be1,
                   (void*)&rm1, (void*)&rv1,
                   (void*)&W2, (void*)&b2, (void*)&g2, (void*)&be2,
                   (void*)&rm2, (void*)&rv2,
                   (void*)&W3, (void*)&b3,
                   (void*)&srcmap, (void*)&lp, (void*)&wa, (void*)&out };

  hipLaunchCooperativeKernel((void*)k_all, dim3(NBLK), dim3(256),
                             args, 0, stream);
}

// Round 8
// 25.911 us; speedup vs baseline: 3.7471x; 3.7471x over previous
//
#include <hip/hip_runtime.h>
#include <math.h>

#define B_    32
#define PPB   256
#define N_    (B_*PPB)     // 8192 proposals / padded slots
#define M_    128
#define LANG_ 256
#define H_    128
#define EPS_  1e-5f
#define MC    16           // columns per MLP block

typedef __attribute__((ext_vector_type(8))) short s16x8;
typedef __attribute__((ext_vector_type(4))) float f32x4;

static __device__ __forceinline__ unsigned short f2bf(float x) {
  unsigned int u = __float_as_uint(x);
  unsigned int r = (u + 0x7fff + ((u >> 16) & 1)) >> 16;
  return (unsigned short)r;
}
static __device__ __forceinline__ float bf2f(unsigned short h) {
  return __uint_as_float(((unsigned int)h) << 16);
}

// ---------------------------------------------------------------------------
// Kernel P: 96 blocks, three independent roles (no cross-block deps):
//   blk  0-31: bin-parallel mapping — block b owns bin b, scans all 8192
//              first-points, ranks members (wave scan), scatters srcmap rows.
//   blk 32-63: frag-major hi/lo bf16 weight build (wa).
//   blk 64-95: lang projection lp[b][o] = Wf[o,128:384].lang[b].
// ---------------------------------------------------------------------------
__global__ __launch_bounds__(256) void k_prep(
    const int* __restrict__ pidx, const int* __restrict__ poff,
    const int* __restrict__ boff, int* __restrict__ srcmap,
    const float* __restrict__ Wf, const float* __restrict__ langg,
    float* __restrict__ lp,
    const float* __restrict__ W1, const float* __restrict__ W2,
    unsigned short* __restrict__ wa)
{
  __shared__ int wtot[4];
  const int tid = threadIdx.x;
  const int lane = tid & 63, wid = tid >> 6;
  const int o16 = lane & 15, g = lane >> 4;
  const int blk = blockIdx.x;

  if (blk < 32) {
    // ---- bin-parallel mapping: block blk owns bin blk
    const int blo = boff[blk], bhi = boff[blk + 1];
    srcmap[blk * PPB + tid] = -1;
    const int i0 = tid * 32;
    unsigned mask = 0u;
    #pragma unroll
    for (int jj = 0; jj < 8; ++jj) {
      const int4 pv = *reinterpret_cast<const int4*>(poff + i0 + jj * 4);
      const int offs[4] = {pv.x, pv.y, pv.z, pv.w};
      #pragma unroll
      for (int e = 0; e < 4; ++e) {
        const int fp = pidx[2 * offs[e] + 1];
        mask |= (fp >= blo && fp < bhi) ? (1u << (jj * 4 + e)) : 0u;
      }
    }
    const int cnt = __popc(mask);
    int sc = cnt;                          // inclusive wave scan
    #pragma unroll
    for (int d = 1; d < 64; d <<= 1) {
      const int v = __shfl_up(sc, d);
      if (lane >= d) sc += v;
    }
    if (lane == 63) wtot[wid] = sc;
    __syncthreads();                       // also orders -1 init vs scatter
    int base = sc - cnt;
    #pragma unroll
    for (int w = 0; w < 4; ++w) if (w < wid) base += wtot[w];
    unsigned m = mask;
    int r = base;
    while (m) {
      const int j = __ffs(m) - 1;
      if (r < PPB) srcmap[blk * PPB + r] = i0 + j;   // OOB dropped (.at.set)
      ++r;
      m &= m - 1;
    }
  } else if (blk < 64) {
    // ---- wa build: 6 frag-groups per block
    for (int sub = wid; sub < 6; sub += 4) {
      const int G = (blk - 32) * 6 + sub;  // 0..191
      const int L = G >> 6, s = (G >> 3) & 7, t = G & 7;
      const float* Wsrc; int str;
      if (L == 0)      { Wsrc = Wf; str = 384; }
      else if (L == 1) { Wsrc = W1; str = H_; }
      else             { Wsrc = W2; str = H_; }
      const int o = t * 16 + o16, sp = s & 3;
      const bool hi = (s < 4);
      const float* rowp = Wsrc + (size_t)o * str + sp * 32 + g * 4;
      const float4 a = *reinterpret_cast<const float4*>(rowp);
      const float4 bq = *reinterpret_cast<const float4*>(rowp + 16);
      const float av[8] = {a.x, a.y, a.z, a.w, bq.x, bq.y, bq.z, bq.w};
      s16x8 v;
      #pragma unroll
      for (int e = 0; e < 8; ++e) {
        const unsigned short h = f2bf(av[e]);
        v[e] = (short)(hi ? h : f2bf(av[e] - bf2f(h)));
      }
      *reinterpret_cast<s16x8*>(wa + (size_t)G * 512 + lane * 8) = v;
    }
  } else {
    // ---- lang projection for batch blk-64: 2 threads per output channel
    const int bb = blk - 64;
    const int o = tid >> 1, hf = tid & 1;
    float acc = 0.f;
    const int l0 = hf * 128;
    #pragma unroll 8
    for (int l = l0; l < l0 + 128; l += 4) {
      const float4 w = *reinterpret_cast<const float4*>(Wf + o * 384 + 128 + l);
      const float4 e = *reinterpret_cast<const float4*>(langg + bb * LANG_ + l);
      acc += w.x * e.x + w.y * e.y + w.z * e.z + w.w * e.w;
    }
    acc += __shfl_xor(acc, 1);
    if (hf == 0) lp[bb * H_ + o] = acc;
  }
}

// ---------------------------------------------------------------------------
// Kernel D: MFMA MLP (r6 verbatim). 512 blocks x 256 threads (2 blocks/CU),
// 16 cols/block. hi/lo bf16 split, 2 K=256 passes/layer. A-frags from wa.
// ---------------------------------------------------------------------------
#define MFMA_LAYER(Aarr)                                                     \
  {                                                                          \
    _Pragma("unroll")                                                        \
    for (int sg = 0; sg < 8; ++sg) {                                         \
      const s16x8 bb = (sg < 4) ? Bh[sg] : Bl[sg - 4];                       \
      acc[0] = __builtin_amdgcn_mfma_f32_16x16x32_bf16(Aarr[0][sg], bb, acc[0], 0, 0, 0); \
      acc[1] = __builtin_amdgcn_mfma_f32_16x16x32_bf16(Aarr[1][sg], bb, acc[1], 0, 0, 0); \
    }                                                                        \
    _Pragma("unroll")                                                        \
    for (int sg = 0; sg < 8; ++sg) {                                         \
      const s16x8 bb = (sg < 4) ? Bl[sg] : Bh[sg - 4];                       \
      acc[0] = __builtin_amdgcn_mfma_f32_16x16x32_bf16(Aarr[0][sg], bb, acc[0], 0, 0, 0); \
      acc[1] = __builtin_amdgcn_mfma_f32_16x16x32_bf16(Aarr[1][sg], bb, acc[1], 0, 0, 0); \
    }                                                                        \
  }

#define READ_B()                                                             \
  {                                                                          \
    _Pragma("unroll")                                                        \
    for (int s = 0; s < 4; ++s) {                                            \
      const int idx = (s * 4 + g) * 16 + o16;                                \
      Bh[s] = XbHi[idx];                                                     \
      Bl[s] = XbLo[idx];                                                     \
    }                                                                        \
  }

#define LOAD_A(Aarr, LL)                                                     \
  {                                                                          \
    _Pragma("unroll")                                                        \
    for (int t = 0; t < 2; ++t)                                              \
      _Pragma("unroll")                                                      \
      for (int s = 0; s < 8; ++s)                                            \
        Aarr[t][s] = *reinterpret_cast<const s16x8*>(                        \
            wa + (size_t)(((LL) * 8 + s) * 8 + (wid * 2 + t)) * 512 + lane * 8); \
  }

__global__ __launch_bounds__(256, 2) void k_mlp(
    const float* __restrict__ feats,
    const unsigned short* __restrict__ wa,
    const float* __restrict__ bf, const float* __restrict__ b1,
    const float* __restrict__ g1, const float* __restrict__ be1,
    const float* __restrict__ rm1, const float* __restrict__ rv1,
    const float* __restrict__ b2, const float* __restrict__ g2,
    const float* __restrict__ be2, const float* __restrict__ rm2,
    const float* __restrict__ rv2,
    const float* __restrict__ W3, const float* __restrict__ b3,
    const int* __restrict__ srcmap, const float* __restrict__ lpg,
    float* __restrict__ out)
{
  __shared__ s16x8 XbHi[256];      // [sg16][n16] frags (4 KB)
  __shared__ s16x8 XbLo[256];      // (4 KB)
  __shared__ float pbuf[1024];
  __shared__ float outp[64];

  const int tid = threadIdx.x;
  const int lane = tid & 63, wid = tid >> 6;
  const int o16 = lane & 15, g = lane >> 4;
  const int q0 = blockIdx.x * MC;
  const int b = blockIdx.x >> 4;   // 16 blocks per batch

  s16x8 A0[2][8], A1[2][8], A2[2][8];
  LOAD_A(A0, 0);                   // in flight under pbuf + feats staging

  #pragma unroll
  for (int j = tid; j < 1024; j += 256) {
    const int arr = j >> 7, o = j & 127;
    float v;
    switch (arr) {
      case 0: v = bf[o] + lpg[b * H_ + o]; break;
      case 1: v = b1[o]; break;
      case 2: v = g1[o] * rsqrtf(rv1[o] + EPS_); break;
      case 3: { const float s = g1[o] * rsqrtf(rv1[o] + EPS_);
                v = be1[o] - rm1[o] * s; } break;
      case 4: v = b2[o]; break;
      case 5: v = g2[o] * rsqrtf(rv2[o] + EPS_); break;
      case 6: { const float s = g2[o] * rsqrtf(rv2[o] + EPS_);
                v = be2[o] - rm2[o] * s; } break;
      default: v = W3[o]; break;
    }
    pbuf[j] = v;
  }

  // gather feats (hi/lo split) into Xb: frag (s,gg) x col n
  {
    const int n = tid & 15, u = tid >> 4;
    const int s = u >> 2, gg = u & 3;
    const int srow = srcmap[q0 + n];
    const int k0 = s * 32 + gg * 4;
    float4 a = make_float4(0.f, 0.f, 0.f, 0.f), bq = a;
    if (srow >= 0) {
      a  = *reinterpret_cast<const float4*>(feats + (size_t)srow * M_ + k0);
      bq = *reinterpret_cast<const float4*>(feats + (size_t)srow * M_ + k0 + 16);
    }
    const float av[8] = {a.x, a.y, a.z, a.w, bq.x, bq.y, bq.z, bq.w};
    s16x8 hv, lv;
    #pragma unroll
    for (int e = 0; e < 8; ++e) {
      const unsigned short h = f2bf(av[e]);
      hv[e] = (short)h;
      lv[e] = (short)f2bf(av[e] - bf2f(h));
    }
    XbHi[u * 16 + n] = hv;
    XbLo[u * 16 + n] = lv;
  }
  __syncthreads();

  f32x4 acc[2];
  s16x8 Bh[4], Bl[4];

  // ================= Layer 0 =================
  READ_B();
  __syncthreads();
  LOAD_A(A1, 1);
  acc[0] = (f32x4){0.f, 0.f, 0.f, 0.f};
  acc[1] = (f32x4){0.f, 0.f, 0.f, 0.f};
  MFMA_LAYER(A0);
  {
    s16x8 hv, lv;
    #pragma unroll
    for (int t = 0; t < 2; ++t)
      #pragma unroll
      for (int r = 0; r < 4; ++r) {
        const int o = (wid * 2 + t) * 16 + g * 4 + r;
        const float v = fmaxf(acc[t][r] + pbuf[o], 0.f);
        const unsigned short h = f2bf(v);
        hv[t * 4 + r] = (short)h;
        lv[t * 4 + r] = (short)f2bf(v - bf2f(h));
      }
    const int widx = (wid * 4 + g) * 16 + o16;
    XbHi[widx] = hv;
    XbLo[widx] = lv;
  }
  __syncthreads();

  // ================= Layer 1 =================
  READ_B();
  __syncthreads();
  LOAD_A(A2, 2);
  acc[0] = (f32x4){0.f, 0.f, 0.f, 0.f};
  acc[1] = (f32x4){0.f, 0.f, 0.f, 0.f};
  MFMA_LAYER(A1);
  {
    s16x8 hv, lv;
    #pragma unroll
    for (int t = 0; t < 2; ++t)
      #pragma unroll
      for (int r = 0; r < 4; ++r) {
        const int o = (wid * 2 + t) * 16 + g * 4 + r;
        const float v = fmaxf(acc[t][r] + pbuf[128 + o], 0.f) * pbuf[256 + o]
                        + pbuf[384 + o];
        const unsigned short h = f2bf(v);
        hv[t * 4 + r] = (short)h;
        lv[t * 4 + r] = (short)f2bf(v - bf2f(h));
      }
    const int widx = (wid * 4 + g) * 16 + o16;
    XbHi[widx] = hv;
    XbLo[widx] = lv;
  }
  __syncthreads();

  // ================= Layer 2 + epilogue =================
  READ_B();
  acc[0] = (f32x4){0.f, 0.f, 0.f, 0.f};
  acc[1] = (f32x4){0.f, 0.f, 0.f, 0.f};
  MFMA_LAYER(A2);
  {
    float p0 = 0.f;
    #pragma unroll
    for (int t = 0; t < 2; ++t)
      #pragma unroll
      for (int r = 0; r < 4; ++r) {
        const int o = (wid * 2 + t) * 16 + g * 4 + r;
        p0 += pbuf[896 + o] *
              (fmaxf(acc[t][r] + pbuf[512 + o], 0.f) * pbuf[640 + o] + pbuf[768 + o]);
      }
    p0 += __shfl_xor(p0, 16);
    p0 += __shfl_xor(p0, 32);
    if (lane < 16) outp[wid * 16 + lane] = p0;
    __syncthreads();
    if (tid < 16)
      out[q0 + tid] = outp[tid] + outp[16 + tid] + outp[32 + tid] + outp[48 + tid] + b3[0];
  }
}

// ---------------------------------------------------------------------------
extern "C" void kernel_launch(void* const* d_in, const int* in_sizes, int n_in,
                              void* d_out, int out_size, void* d_ws, size_t ws_size,
                              hipStream_t stream) {
  const float* feats = (const float*)d_in[0];
  const int*   pidx  = (const int*)d_in[1];
  const int*   poff  = (const int*)d_in[2];
  const int*   boff  = (const int*)d_in[3];
  const float* lang  = (const float*)d_in[4];
  const float* Wf    = (const float*)d_in[5];
  const float* bf    = (const float*)d_in[6];
  const float* W1    = (const float*)d_in[7];
  const float* b1    = (const float*)d_in[8];
  const float* g1    = (const float*)d_in[9];
  const float* be1   = (const float*)d_in[10];
  const float* rm1   = (const float*)d_in[11];
  const float* rv1   = (const float*)d_in[12];
  const float* W2    = (const float*)d_in[13];
  const float* b2    = (const float*)d_in[14];
  const float* g2    = (const float*)d_in[15];
  const float* be2   = (const float*)d_in[16];
  const float* rm2   = (const float*)d_in[17];
  const float* rv2   = (const float*)d_in[18];
  const float* W3    = (const float*)d_in[19];
  const float* b3    = (const float*)d_in[20];
  float* out = (float*)d_out;

  int*            srcmap = (int*)d_ws;                             // 32768 B
  float*          lp     = (float*)((char*)d_ws + 32768);          // 16384 B
  unsigned short* wa     = (unsigned short*)((char*)d_ws + 49152); // 196608 B

  hipLaunchKernelGGL(k_prep, dim3(96), dim3(256), 0, stream,
                     pidx, poff, boff, srcmap, Wf, lang, lp, W1, W2, wa);
  hipLaunchKernelGGL(k_mlp, dim3(N_ / MC), dim3(256), 0, stream,
                     feats, wa, bf, b1, g1, be1, rm1, rv1,
                     b2, g2, be2, rm2, rv2, W3, b3, srcmap, lp, out);
}